// Round 18
// baseline (320.162 us; speedup 1.0000x reference)
//
#include <hip/hip_runtime.h>

#define BN_EPS 1e-5f

typedef __attribute__((ext_vector_type(8))) short bf16x8;
typedef __attribute__((ext_vector_type(4))) float f32x4;
typedef unsigned int uint32;

__device__ __forceinline__ unsigned short f2bf(float f) {
    unsigned u = __float_as_uint(f);
    u += 0x7FFFu + ((u >> 16) & 1u);   // round-to-nearest-even
    return (unsigned short)(u >> 16);
}
__device__ __forceinline__ float bf2f(unsigned short u) {
    return __uint_as_float((unsigned)u << 16);
}
__device__ __forceinline__ float lo_bf(uint32 u) { return __uint_as_float(u << 16); }
__device__ __forceinline__ float hi_bf(uint32 u) { return __uint_as_float(u & 0xFFFF0000u); }
__device__ __forceinline__ uint32 pack_bf(float a0, float a1) {
    return ((uint32)f2bf(a1) << 16) | (uint32)f2bf(a0);
}

// ---------------- coarse histogram (bucket = 256 nodes), LDS-binned ----------------
__global__ __launch_bounds__(256) void count_coarse_kernel(const int* __restrict__ u2,
                                                           int* __restrict__ coarse_cnt, int E) {
    __shared__ int lcnt[256];
    const int tid = threadIdx.x;
    lcnt[tid] = 0;
    __syncthreads();
    const int e0 = blockIdx.x * 4096;
#pragma unroll
    for (int k = 0; k < 16; ++k) {
        int e = e0 + k * 256 + tid;
        if (e < E) atomicAdd(&lcnt[u2[e] >> 8], 1);
    }
    __syncthreads();
    int c = lcnt[tid];
    if (c) atomicAdd(&coarse_cnt[tid], c);
}

// ---------------- pass 1: bin edges by coarse bucket (u>>8), scan of counts in-block ----
// packed edge: (u&255)<<16 | c    (requires c < 65536)
__global__ __launch_bounds__(256) void bin_coarse_kernel(const int* __restrict__ u2,
                                                         const int* __restrict__ c2,
                                                         const int* __restrict__ coarse_cnt,
                                                         int* __restrict__ coarse_alloc,
                                                         int* __restrict__ buck, int E, int nc) {
    __shared__ int sbuf[256];
    __shared__ int lcnt[256];
    __shared__ int lbase[256];
    const int tid = threadIdx.x;
    int cv = (tid < nc) ? coarse_cnt[tid] : 0;
    sbuf[tid] = cv;
    __syncthreads();
    for (int off = 1; off < 256; off <<= 1) {
        int x = (tid >= off) ? sbuf[tid - off] : 0;
        __syncthreads();
        sbuf[tid] += x;
        __syncthreads();
    }
    const int cstart = sbuf[tid] - cv;
    lcnt[tid] = 0;
    __syncthreads();
    const int e0 = blockIdx.x * 4096;
    int ue[16];
#pragma unroll
    for (int k = 0; k < 16; ++k) {
        int e = e0 + k * 256 + tid;
        int u = (e < E) ? u2[e] : -1;
        ue[k] = u;
        if (u >= 0) atomicAdd(&lcnt[u >> 8], 1);
    }
    __syncthreads();
    int c0 = lcnt[tid];
    lbase[tid] = cstart + (c0 ? atomicAdd(&coarse_alloc[tid], c0) : 0);
    lcnt[tid] = 0;
    __syncthreads();
#pragma unroll
    for (int k = 0; k < 16; ++k) {
        int e = e0 + k * 256 + tid;
        if (e < E) {
            int u = ue[k];
            int cb = u >> 8;
            int pos = lbase[cb] + atomicAdd(&lcnt[cb], 1);
            buck[pos] = ((u & 255) << 16) | c2[e];
        }
    }
}

// ---------------- pass 2: per-bucket node histogram + scan -> node_start + csr_src ----------------
__global__ __launch_bounds__(256) void bin_node_kernel(const int* __restrict__ coarse_cnt,
                                                       const int* __restrict__ buck,
                                                       int* __restrict__ node_start,
                                                       int* __restrict__ csr_src, int N, int nc) {
    __shared__ int sbuf[256];
    __shared__ int lcnt[256];
    __shared__ int lcur[256];
    const int cb = blockIdx.x;
    const int tid = threadIdx.x;
    int cv = (tid < nc) ? coarse_cnt[tid] : 0;
    sbuf[tid] = cv;
    __syncthreads();
    for (int off = 1; off < 256; off <<= 1) {
        int x = (tid >= off) ? sbuf[tid - off] : 0;
        __syncthreads();
        sbuf[tid] += x;
        __syncthreads();
    }
    lcnt[tid] = 0;
    __syncthreads();
    const int s = (cb == 0) ? 0 : sbuf[cb - 1];
    const int t_end = sbuf[cb];
    for (int e = s + tid; e < t_end; e += 256)
        atomicAdd(&lcnt[buck[e] >> 16], 1);
    __syncthreads();
    int v = lcnt[tid];
    lcur[tid] = v;
    __syncthreads();
    for (int off = 1; off < 256; off <<= 1) {
        int x = (tid >= off) ? lcur[tid - off] : 0;
        __syncthreads();
        lcur[tid] += x;
        __syncthreads();
    }
    int excl = lcur[tid] - v;
    int gstart = s + excl;
    int idx = cb * 256 + tid;
    if (idx <= N) node_start[idx] = gstart;
    lcur[tid] = gstart;
    __syncthreads();
    for (int e = s + tid; e < t_end; e += 256) {
        int w = buck[e];
        int pos = atomicAdd(&lcur[w >> 16], 1);
        csr_src[pos] = w & 0xFFFF;
    }
}

// ---------------- aggregation: h2 = h + sum_{j->i} h[j] ----------------
// wave = 1 node; 4 quarters x 16 lanes; uint4 per lane -> 4 edge rows per load instr;
// 16 edges in flight (4 independent gathers per lane).
__global__ __launch_bounds__(256) void aggregate_kernel(const unsigned short* __restrict__ h,
                                                        const int* __restrict__ row_start,
                                                        const int* __restrict__ csr_src,
                                                        unsigned short* __restrict__ h2, int N) {
    int node = blockIdx.x * 4 + (threadIdx.x >> 6);
    int lane = threadIdx.x & 63;
    if (node >= N) return;
    const int q = lane >> 4, sl = lane & 15;

    float a0 = 0.f, a1 = 0.f, a2 = 0.f, a3 = 0.f, a4 = 0.f, a5 = 0.f, a6 = 0.f, a7 = 0.f;
    if (q == 0) {   // self term, counted once
        uint4 v = ((const uint4*)(h + (size_t)node * 128))[sl];
        a0 = lo_bf(v.x); a1 = hi_bf(v.x); a2 = lo_bf(v.y); a3 = hi_bf(v.y);
        a4 = lo_bf(v.z); a5 = hi_bf(v.z); a6 = lo_bf(v.w); a7 = hi_bf(v.w);
    }

    const int rs = row_start[node], re = row_start[node + 1];
    int e = rs;
    for (; e + 16 <= re; e += 16) {
        int s0 = csr_src[e + q];
        int s1 = csr_src[e + 4 + q];
        int s2 = csr_src[e + 8 + q];
        int s3 = csr_src[e + 12 + q];
        uint4 v0 = ((const uint4*)(h + (size_t)s0 * 128))[sl];
        uint4 v1 = ((const uint4*)(h + (size_t)s1 * 128))[sl];
        uint4 v2 = ((const uint4*)(h + (size_t)s2 * 128))[sl];
        uint4 v3 = ((const uint4*)(h + (size_t)s3 * 128))[sl];
        a0 += (lo_bf(v0.x) + lo_bf(v1.x)) + (lo_bf(v2.x) + lo_bf(v3.x));
        a1 += (hi_bf(v0.x) + hi_bf(v1.x)) + (hi_bf(v2.x) + hi_bf(v3.x));
        a2 += (lo_bf(v0.y) + lo_bf(v1.y)) + (lo_bf(v2.y) + lo_bf(v3.y));
        a3 += (hi_bf(v0.y) + hi_bf(v1.y)) + (hi_bf(v2.y) + hi_bf(v3.y));
        a4 += (lo_bf(v0.z) + lo_bf(v1.z)) + (lo_bf(v2.z) + lo_bf(v3.z));
        a5 += (hi_bf(v0.z) + hi_bf(v1.z)) + (hi_bf(v2.z) + hi_bf(v3.z));
        a6 += (lo_bf(v0.w) + lo_bf(v1.w)) + (lo_bf(v2.w) + lo_bf(v3.w));
        a7 += (hi_bf(v0.w) + hi_bf(v1.w)) + (hi_bf(v2.w) + hi_bf(v3.w));
    }
    for (; e + 8 <= re; e += 8) {
        int s0 = csr_src[e + q];
        int s1 = csr_src[e + 4 + q];
        uint4 v = ((const uint4*)(h + (size_t)s0 * 128))[sl];
        uint4 w = ((const uint4*)(h + (size_t)s1 * 128))[sl];
        a0 += lo_bf(v.x) + lo_bf(w.x); a1 += hi_bf(v.x) + hi_bf(w.x);
        a2 += lo_bf(v.y) + lo_bf(w.y); a3 += hi_bf(v.y) + hi_bf(w.y);
        a4 += lo_bf(v.z) + lo_bf(w.z); a5 += hi_bf(v.z) + hi_bf(w.z);
        a6 += lo_bf(v.w) + lo_bf(w.w); a7 += hi_bf(v.w) + hi_bf(w.w);
    }
    for (; e + 4 <= re; e += 4) {
        int s0 = csr_src[e + q];
        uint4 v = ((const uint4*)(h + (size_t)s0 * 128))[sl];
        a0 += lo_bf(v.x); a1 += hi_bf(v.x); a2 += lo_bf(v.y); a3 += hi_bf(v.y);
        a4 += lo_bf(v.z); a5 += hi_bf(v.z); a6 += lo_bf(v.w); a7 += hi_bf(v.w);
    }
    if (q < re - e) {
        int s0 = csr_src[e + q];
        uint4 v = ((const uint4*)(h + (size_t)s0 * 128))[sl];
        a0 += lo_bf(v.x); a1 += hi_bf(v.x); a2 += lo_bf(v.y); a3 += hi_bf(v.y);
        a4 += lo_bf(v.z); a5 += hi_bf(v.z); a6 += lo_bf(v.w); a7 += hi_bf(v.w);
    }

    a0 += __shfl_xor(a0, 16, 64); a0 += __shfl_xor(a0, 32, 64);
    a1 += __shfl_xor(a1, 16, 64); a1 += __shfl_xor(a1, 32, 64);
    a2 += __shfl_xor(a2, 16, 64); a2 += __shfl_xor(a2, 32, 64);
    a3 += __shfl_xor(a3, 16, 64); a3 += __shfl_xor(a3, 32, 64);
    a4 += __shfl_xor(a4, 16, 64); a4 += __shfl_xor(a4, 32, 64);
    a5 += __shfl_xor(a5, 16, 64); a5 += __shfl_xor(a5, 32, 64);
    a6 += __shfl_xor(a6, 16, 64); a6 += __shfl_xor(a6, 32, 64);
    a7 += __shfl_xor(a7, 16, 64); a7 += __shfl_xor(a7, 32, 64);

    if (q == 0) {
        uint4 o;
        o.x = pack_bf(a0, a1); o.y = pack_bf(a2, a3);
        o.z = pack_bf(a4, a5); o.w = pack_bf(a6, a7);
        ((uint4*)(h2 + (size_t)node * 128))[sl] = o;
    }
}

// ---------------- prep: weight transposes (f32 -> bf16 [OUT][K], PRE-SWIZZLED) + BN fold ----
// byte position of element (row=c, k): ((c*K+k)*2) ^ ((c&7)<<4)
__global__ void prep_kernel(const float* __restrict__ We, const float* __restrict__ W1,
                            const float* __restrict__ W2,
                            unsigned short* __restrict__ Wte,
                            unsigned short* __restrict__ Wt1,
                            unsigned short* __restrict__ Wt2,
                            const float* __restrict__ be,
                            const float* __restrict__ b1, const float* __restrict__ g1,
                            const float* __restrict__ bt1, const float* __restrict__ m1,
                            const float* __restrict__ v1,
                            const float* __restrict__ b2, const float* __restrict__ g2,
                            const float* __restrict__ bt2, const float* __restrict__ m2,
                            const float* __restrict__ v2,
                            float* __restrict__ sce, float* __restrict__ she,
                            float* __restrict__ sc1, float* __restrict__ sh1,
                            float* __restrict__ sc2, float* __restrict__ sh2, int L) {
    int y = blockIdx.y;
    int t = threadIdx.x;
    if (blockIdx.x == 0) {
        if (y == 0) {
            if (t < 128) { sce[t] = 1.f; she[t] = be[t]; }
        } else if (y <= L) {
            int o = (y - 1) * 256 + t;
            float s = g1[o] * rsqrtf(v1[o] + BN_EPS);
            sc1[o] = s;
            sh1[o] = (b1[o] - m1[o]) * s + bt1[o];
        } else {
            if (t < 128) {
                int o = (y - L - 1) * 128 + t;
                float s = g2[o] * rsqrtf(v2[o] + BN_EPS);
                sc2[o] = s;
                sh2[o] = (b2[o] - m2[o]) * s + bt2[o];
            }
        }
    }
    const float* src;
    unsigned short* dst;
    int K;
    if (y == 0)      { src = We; dst = Wte; K = 128; }
    else if (y <= L) { int l = y - 1;     src = W1 + (size_t)l * 128 * 256; dst = Wt1 + (size_t)l * 128 * 256; K = 128; }
    else             { int l = y - L - 1; src = W2 + (size_t)l * 256 * 128; dst = Wt2 + (size_t)l * 256 * 128; K = 256; }
    int idx = blockIdx.x * 256 + t;
    int OUT = 32768 / K;
    if (y == 0) { if (idx >= 128 * 128) return; OUT = 128; }
    int c = idx / K, k = idx % K;
    unsigned byte = ((unsigned)(idx * 2)) ^ (((unsigned)c & 7u) << 4);
    *(unsigned short*)((char*)dst + byte) = f2bf(src[(size_t)k * OUT + c]);
}

// ---------------- MFMA GEMM: C = act(A[nrows,K] @ W[K,OUT] * scale + shift) ----------------
// Wt bf16 [OUT][K] PRE-SWIZZLED -> linear global_load_lds staging; ds_read XOR-swizzled.
// 4 waves column-split (each owns OUT/4 cols) x 4 row-groups = 64 rows/block.
// Each Wt ds_read feeds 4 MFMAs (was 2) -> halves CU LDS-read cycles per output row.
template <int K, int OUT, bool RELU, bool A_F32>
__global__ __launch_bounds__(256) void mfma_gemm_kernel(
    const void* __restrict__ Ap, const unsigned short* __restrict__ Wt,
    const float* __restrict__ scale, const float* __restrict__ shift,
    unsigned short* __restrict__ Cout, int nrows)
{
    constexpr int NT = OUT / 64;    // col tiles of 16 per wave (col-split 4)
    constexpr int KS = K / 32;      // k-steps of 32
    constexpr int RG = 4;           // row groups per wave
    constexpr int CH = OUT * K / 8; // 16B chunks of Wt
    __shared__ unsigned short WtLds[OUT * K];   // <= 64 KB

    const int tid = threadIdx.x;
    const int wv = tid >> 6, lane = tid & 63;
    {
#pragma unroll
        for (int i = 0; i < CH / 256; ++i) {
            unsigned chunk = (unsigned)(i * 256 + wv * 64);
            const char* gsrc = (const char*)Wt + (size_t)(chunk + lane) * 16u;
            char* ldst = (char*)WtLds + (size_t)chunk * 16u;
            __builtin_amdgcn_global_load_lds(
                (const __attribute__((address_space(1))) void*)gsrc,
                (__attribute__((address_space(3))) void*)ldst,
                16, 0, 0);
        }
    }

    const int l15 = lane & 15, lhi = lane >> 4;
    const int wc0 = wv * (OUT / 4);        // this wave's first output column
    const int rbase = blockIdx.x * 64;

    bf16x8 bfrag[RG][KS];
#pragma unroll
    for (int rg = 0; rg < RG; ++rg) {
        const int rr = min(rbase + rg * 16 + l15, nrows - 1);
        if constexpr (A_F32) {
            const float* arow = (const float*)Ap + (size_t)rr * K + lhi * 8;
#pragma unroll
            for (int ks = 0; ks < KS; ++ks) {
                float4 u0 = *(const float4*)(arow + ks * 32);
                float4 u1 = *(const float4*)(arow + ks * 32 + 4);
                bf16x8 f;
                f[0] = (short)f2bf(u0.x); f[1] = (short)f2bf(u0.y);
                f[2] = (short)f2bf(u0.z); f[3] = (short)f2bf(u0.w);
                f[4] = (short)f2bf(u1.x); f[5] = (short)f2bf(u1.y);
                f[6] = (short)f2bf(u1.z); f[7] = (short)f2bf(u1.w);
                bfrag[rg][ks] = f;
            }
        } else {
            const unsigned short* arow = (const unsigned short*)Ap + (size_t)rr * K + lhi * 8;
#pragma unroll
            for (int ks = 0; ks < KS; ++ks)
                bfrag[rg][ks] = *(const bf16x8*)(arow + ks * 32);
        }
    }

    __syncthreads();   // drains vmcnt incl. global_load_lds before ds_read

    f32x4 acc[RG][NT];
#pragma unroll
    for (int rg = 0; rg < RG; ++rg)
#pragma unroll
        for (int nt = 0; nt < NT; ++nt) acc[rg][nt] = (f32x4){0.f, 0.f, 0.f, 0.f};

#pragma unroll
    for (int ks = 0; ks < KS; ++ks) {
#pragma unroll
        for (int nt = 0; nt < NT; ++nt) {
            int row = wc0 + nt * 16 + l15;
            unsigned off = ((unsigned)((row * K + ks * 32 + lhi * 8) * 2)) ^ (((unsigned)(l15 & 7u)) << 4);
            bf16x8 wfrag = *(const bf16x8*)((const char*)WtLds + off);
#pragma unroll
            for (int rg = 0; rg < RG; ++rg)
                acc[rg][nt] = __builtin_amdgcn_mfma_f32_16x16x32_bf16(wfrag, bfrag[rg][ks], acc[rg][nt], 0, 0, 0);
        }
    }

    const float4* sc4 = (const float4*)scale;
    const float4* sh4 = (const float4*)shift;
#pragma unroll
    for (int rg = 0; rg < RG; ++rg) {
        const int r = rbase + rg * 16 + l15;
        if (r >= nrows) continue;
#pragma unroll
        for (int nt = 0; nt < NT; ++nt) {
            const int cq = wc0 / 4 + nt * 4 + lhi;
            float4 sc = sc4[cq];
            float4 sh = sh4[cq];
            float y0 = acc[rg][nt][0] * sc.x + sh.x;
            float y1 = acc[rg][nt][1] * sc.y + sh.y;
            float y2 = acc[rg][nt][2] * sc.z + sh.z;
            float y3 = acc[rg][nt][3] * sc.w + sh.w;
            if (RELU) {
                y0 = fmaxf(y0, 0.f); y1 = fmaxf(y1, 0.f);
                y2 = fmaxf(y2, 0.f); y3 = fmaxf(y3, 0.f);
            }
            size_t o = (size_t)r * OUT + wc0 + nt * 16 + lhi * 4;
            ushort4 p = make_ushort4(f2bf(y0), f2bf(y1), f2bf(y2), f2bf(y3));
            *(ushort4*)(Cout + o) = p;
        }
    }
}

// ---------------- pooling over sorted batch: chunked + boundary atomics ----------------
__global__ __launch_bounds__(128) void pool_kernel(const unsigned short* __restrict__ h,
                                                   const int* __restrict__ batch,
                                                   float* __restrict__ pooled, int N, int chunk) {
    int d = threadIdx.x;
    int start = blockIdx.x * chunk;
    if (start >= N) return;
    int end = min(start + chunk, N);
    float acc = 0.f;
    int g = batch[start];
    for (int r = start; r < end; ++r) {
        int bg = batch[r];
        if (bg != g) {
            atomicAdd(&pooled[g * 128 + d], acc);
            acc = 0.f;
            g = bg;
        }
        acc += bf2f(h[(size_t)r * 128 + d]);
    }
    atomicAdd(&pooled[g * 128 + d], acc);
}

// ---------------- readout MLP ----------------
__global__ __launch_bounds__(128) void readout_kernel(const float* __restrict__ pooled,
                                                      const float* __restrict__ Wr1,
                                                      const float* __restrict__ br1,
                                                      const float* __restrict__ Wr2,
                                                      const float* __restrict__ br2,
                                                      float* __restrict__ out) {
    __shared__ float prow[128];
    __shared__ float t[128];
    int g = blockIdx.x, j = threadIdx.x;
    prow[j] = pooled[g * 128 + j];
    __syncthreads();
    float acc = 0.f;
    for (int k = 0; k < 128; ++k) acc += prow[k] * Wr1[k * 128 + j];
    t[j] = fmaxf(acc + br1[j], 0.f);
    __syncthreads();
    if (j < 10) {
        float a2 = 0.f;
        for (int k = 0; k < 128; ++k) a2 += t[k] * Wr2[k * 10 + j];
        out[g * 10 + j] = a2 + br2[j];
    }
}

extern "C" void kernel_launch(void* const* d_in, const int* in_sizes, int n_in,
                              void* d_out, int out_size, void* d_ws, size_t ws_size,
                              hipStream_t stream) {
    const float* x   = (const float*)d_in[0];
    const int* c2    = (const int*)d_in[1];
    const int* u2    = (const int*)d_in[2];
    const int* batch = (const int*)d_in[3];
    const float* We  = (const float*)d_in[4];
    const float* be  = (const float*)d_in[5];
    const float* W1  = (const float*)d_in[6];
    const float* b1  = (const float*)d_in[7];
    const float* g1  = (const float*)d_in[8];
    const float* bt1 = (const float*)d_in[9];
    const float* m1  = (const float*)d_in[10];
    const float* v1  = (const float*)d_in[11];
    const float* W2  = (const float*)d_in[12];
    const float* b2  = (const float*)d_in[13];
    const float* g2  = (const float*)d_in[14];
    const float* bt2 = (const float*)d_in[15];
    const float* m2  = (const float*)d_in[16];
    const float* v2  = (const float*)d_in[17];
    const float* Wr1 = (const float*)d_in[18];
    const float* br1 = (const float*)d_in[19];
    const float* Wr2 = (const float*)d_in[20];
    const float* br2 = (const float*)d_in[21];

    const int N = in_sizes[3];        // 50000
    const int E = in_sizes[1];        // 800000
    const int L = in_sizes[7] / 256;  // 3
    const int G = out_size / 10;      // 64

    const int NC = (N + 255) / 256;   // 196 coarse buckets (256 nodes each)

    // workspace layout (256B-aligned chunks)
    char* ws = (char*)d_ws;
    size_t off = 0;
    auto alloc = [&](size_t bytes) { char* p = ws + off; off += (bytes + 255) & ~(size_t)255; return p; };
    unsigned short* hb   = (unsigned short*)alloc((size_t)N * 128 * 2);
    unsigned short* h2b  = (unsigned short*)alloc((size_t)N * 128 * 2);
    unsigned short* zb   = (unsigned short*)alloc((size_t)N * 256 * 2);
    unsigned short* Wte  = (unsigned short*)alloc(128 * 128 * 2);
    unsigned short* Wt1  = (unsigned short*)alloc((size_t)L * 256 * 128 * 2);
    unsigned short* Wt2  = (unsigned short*)alloc((size_t)L * 128 * 256 * 2);
    float* sce = (float*)alloc(128 * 4);
    float* she = (float*)alloc(128 * 4);
    float* sc1 = (float*)alloc((size_t)L * 256 * 4);
    float* sh1 = (float*)alloc((size_t)L * 256 * 4);
    float* sc2 = (float*)alloc((size_t)L * 128 * 4);
    float* sh2 = (float*)alloc((size_t)L * 128 * 4);
    float* pooled = (float*)alloc((size_t)G * 128 * 4);
    int* coarse_cnt   = (int*)alloc(512 * 4);       // [0:256) cnt, [256:512) alloc
    int* coarse_alloc = coarse_cnt + 256;
    int* node_start   = (int*)alloc((size_t)(N + 1) * 4);
    int* buck         = (int*)alloc((size_t)E * 4);
    int* csr_src      = (int*)alloc((size_t)E * 4);

    const int ebins = (E + 4095) / 4096;   // 196

    // ---- CSR build: coarse histogram -> 2-pass L2-local counting sort (scan in-block) ----
    hipMemsetAsync(coarse_cnt, 0, 512 * 4, stream);
    hipMemsetAsync(pooled, 0, (size_t)G * 128 * 4, stream);
    count_coarse_kernel<<<ebins, 256, 0, stream>>>(u2, coarse_cnt, E);
    bin_coarse_kernel<<<ebins, 256, 0, stream>>>(u2, c2, coarse_cnt, coarse_alloc, buck, E, NC);
    bin_node_kernel<<<NC, 256, 0, stream>>>(coarse_cnt, buck, node_start, csr_src, N, NC);

    // ---- prep: transposes (pre-swizzled) + BN folds (one launch) ----
    prep_kernel<<<dim3((256 * 128 + 255) / 256, 1 + 2 * L), 256, 0, stream>>>(
        We, W1, W2, Wte, Wt1, Wt2,
        be, b1, g1, bt1, m1, v1, b2, g2, bt2, m2, v2,
        sce, she, sc1, sh1, sc2, sh2, L);

    const int gemm_blocks = (N + 63) / 64;   // 782

    // ---- embed: h = x @ We + be  (reads f32 x directly) ----
    mfma_gemm_kernel<128, 128, false, true><<<gemm_blocks, 256, 0, stream>>>(
        x, Wte, sce, she, hb, N);

    // ---- GIN layers ----
    for (int l = 0; l < L; ++l) {
        aggregate_kernel<<<(N + 3) / 4, 256, 0, stream>>>(hb, node_start, csr_src, h2b, N);
        mfma_gemm_kernel<128, 256, true, false><<<gemm_blocks, 256, 0, stream>>>(
            h2b, Wt1 + (size_t)l * 128 * 256, sc1 + l * 256, sh1 + l * 256, zb, N);
        mfma_gemm_kernel<256, 128, true, false><<<gemm_blocks, 256, 0, stream>>>(
            zb, Wt2 + (size_t)l * 256 * 128, sc2 + l * 128, sh2 + l * 128, hb, N);
    }

    // ---- pooling + readout ----
    const int pool_blocks = 2048;
    const int chunk = (N + pool_blocks - 1) / pool_blocks;
    pool_kernel<<<pool_blocks, 128, 0, stream>>>(hb, batch, pooled, N, chunk);
    readout_kernel<<<G, 128, 0, stream>>>(pooled, Wr1, br1, Wr2, br2, (float*)d_out);
}

// Round 19
// 266.880 us; speedup vs baseline: 1.1996x; 1.1996x over previous
//
#include <hip/hip_runtime.h>

#define BN_EPS 1e-5f

typedef __attribute__((ext_vector_type(8))) short bf16x8;
typedef __attribute__((ext_vector_type(4))) float f32x4;
typedef unsigned int uint32;

__device__ __forceinline__ unsigned short f2bf(float f) {
    unsigned u = __float_as_uint(f);
    u += 0x7FFFu + ((u >> 16) & 1u);   // round-to-nearest-even
    return (unsigned short)(u >> 16);
}
__device__ __forceinline__ float bf2f(unsigned short u) {
    return __uint_as_float((unsigned)u << 16);
}
__device__ __forceinline__ float lo_bf(uint32 u) { return __uint_as_float(u << 16); }
__device__ __forceinline__ float hi_bf(uint32 u) { return __uint_as_float(u & 0xFFFF0000u); }
__device__ __forceinline__ uint32 pack_bf(float a0, float a1) {
    return ((uint32)f2bf(a1) << 16) | (uint32)f2bf(a0);
}

// ---------------- setup A: count_coarse (blocks [0,nca)) || prep (blocks [nca, nca+896)) ----
__global__ __launch_bounds__(256) void setup_a_kernel(
    const int* __restrict__ u2, int* __restrict__ coarse_cnt, int E, int nca,
    const float* __restrict__ We, const float* __restrict__ W1, const float* __restrict__ W2,
    unsigned short* __restrict__ Wte, unsigned short* __restrict__ Wt1,
    unsigned short* __restrict__ Wt2,
    const float* __restrict__ be,
    const float* __restrict__ b1, const float* __restrict__ g1, const float* __restrict__ bt1,
    const float* __restrict__ m1, const float* __restrict__ v1,
    const float* __restrict__ b2, const float* __restrict__ g2, const float* __restrict__ bt2,
    const float* __restrict__ m2, const float* __restrict__ v2,
    float* __restrict__ sce, float* __restrict__ she,
    float* __restrict__ sc1, float* __restrict__ sh1,
    float* __restrict__ sc2, float* __restrict__ sh2, int L)
{
    __shared__ int lcnt[256];
    const int t = threadIdx.x;
    if ((int)blockIdx.x < nca) {
        // ---- coarse histogram (bucket = 256 nodes), LDS-binned ----
        lcnt[t] = 0;
        __syncthreads();
        const int e0 = blockIdx.x * 4096;
#pragma unroll
        for (int k = 0; k < 16; ++k) {
            int e = e0 + k * 256 + t;
            if (e < E) atomicAdd(&lcnt[u2[e] >> 8], 1);
        }
        __syncthreads();
        int c = lcnt[t];
        if (c) atomicAdd(&coarse_cnt[t], c);
        return;
    }
    // ---- prep: weight transposes (f32 -> bf16 [OUT][K], PRE-SWIZZLED) + BN fold ----
    const int pb = blockIdx.x - nca;
    const int y = pb >> 7;      // 0..2L
    const int bx = pb & 127;
    if (bx == 0) {
        if (y == 0) {
            if (t < 128) { sce[t] = 1.f; she[t] = be[t]; }
        } else if (y <= L) {
            int o = (y - 1) * 256 + t;
            float s = g1[o] * rsqrtf(v1[o] + BN_EPS);
            sc1[o] = s;
            sh1[o] = (b1[o] - m1[o]) * s + bt1[o];
        } else {
            if (t < 128) {
                int o = (y - L - 1) * 128 + t;
                float s = g2[o] * rsqrtf(v2[o] + BN_EPS);
                sc2[o] = s;
                sh2[o] = (b2[o] - m2[o]) * s + bt2[o];
            }
        }
    }
    const float* src;
    unsigned short* dst;
    int K;
    if (y == 0)      { src = We; dst = Wte; K = 128; }
    else if (y <= L) { int l = y - 1;     src = W1 + (size_t)l * 128 * 256; dst = Wt1 + (size_t)l * 128 * 256; K = 128; }
    else             { int l = y - L - 1; src = W2 + (size_t)l * 256 * 128; dst = Wt2 + (size_t)l * 256 * 128; K = 256; }
    int idx = bx * 256 + t;
    int OUT = 32768 / K;
    if (y == 0) { if (idx >= 128 * 128) return; OUT = 128; }
    int c = idx / K, k = idx % K;
    unsigned byte = ((unsigned)(idx * 2)) ^ (((unsigned)c & 7u) << 4);
    *(unsigned short*)((char*)dst + byte) = f2bf(src[(size_t)k * OUT + c]);
}

// ---------------- setup B: bin_coarse (blocks [0,nca)) || embed GEMM (blocks [nca, nca+ngemm)) ----
// bin_coarse: packed edge (u&255)<<16 | c. embed: h = x @ We + be  (K=128, OUT=128, A f32).
__global__ __launch_bounds__(256) void setup_b_kernel(
    const int* __restrict__ u2, const int* __restrict__ c2,
    const int* __restrict__ coarse_cnt, int* __restrict__ coarse_alloc,
    int* __restrict__ buck, int E, int nc, int nca,
    const float* __restrict__ x, const unsigned short* __restrict__ Wte,
    const float* __restrict__ sce, const float* __restrict__ she,
    unsigned short* __restrict__ hb, int nrows)
{
    __shared__ unsigned short WtLds[128 * 128];   // 32 KB (embed path)
    __shared__ int sbuf[256];
    __shared__ int lcnt[256];
    __shared__ int lbase[256];
    const int tid = threadIdx.x;

    if ((int)blockIdx.x < nca) {
        // ---- bin_coarse body ----
        int cv = (tid < nc) ? coarse_cnt[tid] : 0;
        sbuf[tid] = cv;
        __syncthreads();
        for (int off = 1; off < 256; off <<= 1) {
            int xv = (tid >= off) ? sbuf[tid - off] : 0;
            __syncthreads();
            sbuf[tid] += xv;
            __syncthreads();
        }
        const int cstart = sbuf[tid] - cv;
        lcnt[tid] = 0;
        __syncthreads();
        const int e0 = blockIdx.x * 4096;
        int ue[16];
#pragma unroll
        for (int k = 0; k < 16; ++k) {
            int e = e0 + k * 256 + tid;
            int u = (e < E) ? u2[e] : -1;
            ue[k] = u;
            if (u >= 0) atomicAdd(&lcnt[u >> 8], 1);
        }
        __syncthreads();
        int c0 = lcnt[tid];
        lbase[tid] = cstart + (c0 ? atomicAdd(&coarse_alloc[tid], c0) : 0);
        lcnt[tid] = 0;
        __syncthreads();
#pragma unroll
        for (int k = 0; k < 16; ++k) {
            int e = e0 + k * 256 + tid;
            if (e < E) {
                int u = ue[k];
                int cb = u >> 8;
                int pos = lbase[cb] + atomicAdd(&lcnt[cb], 1);
                buck[pos] = ((u & 255) << 16) | c2[e];
            }
        }
        return;
    }

    // ---- embed GEMM body (K=128, OUT=128, RELU=false, A f32) ----
    constexpr int K = 128, OUT = 128;
    constexpr int NT = OUT / 16;    // 8
    constexpr int KS = K / 32;      // 4
    constexpr int CH = OUT * K / 8; // 2048
    const int bid = blockIdx.x - nca;
    const int wv = tid >> 6, lane = tid & 63;
    {
#pragma unroll
        for (int i = 0; i < CH / 256; ++i) {
            unsigned chunk = (unsigned)(i * 256 + wv * 64);
            const char* gsrc = (const char*)Wte + (size_t)(chunk + lane) * 16u;
            char* ldst = (char*)WtLds + (size_t)chunk * 16u;
            __builtin_amdgcn_global_load_lds(
                (const __attribute__((address_space(1))) void*)gsrc,
                (__attribute__((address_space(3))) void*)ldst,
                16, 0, 0);
        }
    }

    const int l15 = lane & 15, lhi = lane >> 4;
    const int rbase = bid * 128 + wv * 32;
    const int r0 = rbase + l15;
    const int r1 = rbase + 16 + l15;
    const int rr0 = min(r0, nrows - 1);
    const int rr1 = min(r1, nrows - 1);

    bf16x8 bfrag[2][KS];
    {
        const float* a0 = x + (size_t)rr0 * K + lhi * 8;
        const float* a1 = x + (size_t)rr1 * K + lhi * 8;
#pragma unroll
        for (int ks = 0; ks < KS; ++ks) {
            float4 u0 = *(const float4*)(a0 + ks * 32);
            float4 u1 = *(const float4*)(a0 + ks * 32 + 4);
            float4 w0 = *(const float4*)(a1 + ks * 32);
            float4 w1 = *(const float4*)(a1 + ks * 32 + 4);
            bf16x8 f, g;
            f[0] = (short)f2bf(u0.x); f[1] = (short)f2bf(u0.y);
            f[2] = (short)f2bf(u0.z); f[3] = (short)f2bf(u0.w);
            f[4] = (short)f2bf(u1.x); f[5] = (short)f2bf(u1.y);
            f[6] = (short)f2bf(u1.z); f[7] = (short)f2bf(u1.w);
            g[0] = (short)f2bf(w0.x); g[1] = (short)f2bf(w0.y);
            g[2] = (short)f2bf(w0.z); g[3] = (short)f2bf(w0.w);
            g[4] = (short)f2bf(w1.x); g[5] = (short)f2bf(w1.y);
            g[6] = (short)f2bf(w1.z); g[7] = (short)f2bf(w1.w);
            bfrag[0][ks] = f;
            bfrag[1][ks] = g;
        }
    }

    __syncthreads();

    f32x4 acc[2][NT];
#pragma unroll
    for (int g = 0; g < 2; ++g)
#pragma unroll
        for (int nt = 0; nt < NT; ++nt) acc[g][nt] = (f32x4){0.f, 0.f, 0.f, 0.f};

#pragma unroll
    for (int ks = 0; ks < KS; ++ks) {
#pragma unroll
        for (int nt = 0; nt < NT; ++nt) {
            int row = nt * 16 + l15;
            unsigned off = ((unsigned)((row * K + ks * 32 + lhi * 8) * 2)) ^ (((unsigned)(l15 & 7u)) << 4);
            bf16x8 wfrag = *(const bf16x8*)((const char*)WtLds + off);
            acc[0][nt] = __builtin_amdgcn_mfma_f32_16x16x32_bf16(wfrag, bfrag[0][ks], acc[0][nt], 0, 0, 0);
            acc[1][nt] = __builtin_amdgcn_mfma_f32_16x16x32_bf16(wfrag, bfrag[1][ks], acc[1][nt], 0, 0, 0);
        }
    }

    const float4* sc4 = (const float4*)sce;
    const float4* sh4 = (const float4*)she;
#pragma unroll
    for (int g = 0; g < 2; ++g) {
        const int r = (g == 0) ? r0 : r1;
        if (r >= nrows) continue;
#pragma unroll
        for (int nt = 0; nt < NT; ++nt) {
            float4 sc = sc4[nt * 4 + lhi];
            float4 sh = sh4[nt * 4 + lhi];
            float y0 = acc[g][nt][0] * sc.x + sh.x;
            float y1 = acc[g][nt][1] * sc.y + sh.y;
            float y2 = acc[g][nt][2] * sc.z + sh.z;
            float y3 = acc[g][nt][3] * sc.w + sh.w;
            size_t o = (size_t)r * OUT + nt * 16 + lhi * 4;
            ushort4 p = make_ushort4(f2bf(y0), f2bf(y1), f2bf(y2), f2bf(y3));
            *(ushort4*)(hb + o) = p;
        }
    }
}

// ---------------- pass 2: per-bucket node histogram + scan -> node_start + csr_src ----------------
__global__ __launch_bounds__(256) void bin_node_kernel(const int* __restrict__ coarse_cnt,
                                                       const int* __restrict__ buck,
                                                       int* __restrict__ node_start,
                                                       int* __restrict__ csr_src, int N, int nc) {
    __shared__ int sbuf[256];
    __shared__ int lcnt[256];
    __shared__ int lcur[256];
    const int cb = blockIdx.x;
    const int tid = threadIdx.x;
    int cv = (tid < nc) ? coarse_cnt[tid] : 0;
    sbuf[tid] = cv;
    __syncthreads();
    for (int off = 1; off < 256; off <<= 1) {
        int x = (tid >= off) ? sbuf[tid - off] : 0;
        __syncthreads();
        sbuf[tid] += x;
        __syncthreads();
    }
    lcnt[tid] = 0;
    __syncthreads();
    const int s = (cb == 0) ? 0 : sbuf[cb - 1];
    const int t_end = sbuf[cb];
    for (int e = s + tid; e < t_end; e += 256)
        atomicAdd(&lcnt[buck[e] >> 16], 1);
    __syncthreads();
    int v = lcnt[tid];
    lcur[tid] = v;
    __syncthreads();
    for (int off = 1; off < 256; off <<= 1) {
        int x = (tid >= off) ? lcur[tid - off] : 0;
        __syncthreads();
        lcur[tid] += x;
        __syncthreads();
    }
    int excl = lcur[tid] - v;
    int gstart = s + excl;
    int idx = cb * 256 + tid;
    if (idx <= N) node_start[idx] = gstart;
    lcur[tid] = gstart;
    __syncthreads();
    for (int e = s + tid; e < t_end; e += 256) {
        int w = buck[e];
        int pos = atomicAdd(&lcur[w >> 16], 1);
        csr_src[pos] = w & 0xFFFF;
    }
}

// ---------------- aggregation: h2 = h + sum_{j->i} h[j] ----------------
// wave = 1 node; 4 quarters x 16 lanes; uint4 per lane -> 4 edge rows per load instr;
// 16 edges in flight (4 independent gathers per lane).
__global__ __launch_bounds__(256) void aggregate_kernel(const unsigned short* __restrict__ h,
                                                        const int* __restrict__ row_start,
                                                        const int* __restrict__ csr_src,
                                                        unsigned short* __restrict__ h2, int N) {
    int node = blockIdx.x * 4 + (threadIdx.x >> 6);
    int lane = threadIdx.x & 63;
    if (node >= N) return;
    const int q = lane >> 4, sl = lane & 15;

    float a0 = 0.f, a1 = 0.f, a2 = 0.f, a3 = 0.f, a4 = 0.f, a5 = 0.f, a6 = 0.f, a7 = 0.f;
    if (q == 0) {   // self term, counted once
        uint4 v = ((const uint4*)(h + (size_t)node * 128))[sl];
        a0 = lo_bf(v.x); a1 = hi_bf(v.x); a2 = lo_bf(v.y); a3 = hi_bf(v.y);
        a4 = lo_bf(v.z); a5 = hi_bf(v.z); a6 = lo_bf(v.w); a7 = hi_bf(v.w);
    }

    const int rs = row_start[node], re = row_start[node + 1];
    int e = rs;
    for (; e + 16 <= re; e += 16) {
        int s0 = csr_src[e + q];
        int s1 = csr_src[e + 4 + q];
        int s2 = csr_src[e + 8 + q];
        int s3 = csr_src[e + 12 + q];
        uint4 v0 = ((const uint4*)(h + (size_t)s0 * 128))[sl];
        uint4 v1 = ((const uint4*)(h + (size_t)s1 * 128))[sl];
        uint4 v2 = ((const uint4*)(h + (size_t)s2 * 128))[sl];
        uint4 v3 = ((const uint4*)(h + (size_t)s3 * 128))[sl];
        a0 += (lo_bf(v0.x) + lo_bf(v1.x)) + (lo_bf(v2.x) + lo_bf(v3.x));
        a1 += (hi_bf(v0.x) + hi_bf(v1.x)) + (hi_bf(v2.x) + hi_bf(v3.x));
        a2 += (lo_bf(v0.y) + lo_bf(v1.y)) + (lo_bf(v2.y) + lo_bf(v3.y));
        a3 += (hi_bf(v0.y) + hi_bf(v1.y)) + (hi_bf(v2.y) + hi_bf(v3.y));
        a4 += (lo_bf(v0.z) + lo_bf(v1.z)) + (lo_bf(v2.z) + lo_bf(v3.z));
        a5 += (hi_bf(v0.z) + hi_bf(v1.z)) + (hi_bf(v2.z) + hi_bf(v3.z));
        a6 += (lo_bf(v0.w) + lo_bf(v1.w)) + (lo_bf(v2.w) + lo_bf(v3.w));
        a7 += (hi_bf(v0.w) + hi_bf(v1.w)) + (hi_bf(v2.w) + hi_bf(v3.w));
    }
    for (; e + 8 <= re; e += 8) {
        int s0 = csr_src[e + q];
        int s1 = csr_src[e + 4 + q];
        uint4 v = ((const uint4*)(h + (size_t)s0 * 128))[sl];
        uint4 w = ((const uint4*)(h + (size_t)s1 * 128))[sl];
        a0 += lo_bf(v.x) + lo_bf(w.x); a1 += hi_bf(v.x) + hi_bf(w.x);
        a2 += lo_bf(v.y) + lo_bf(w.y); a3 += hi_bf(v.y) + hi_bf(w.y);
        a4 += lo_bf(v.z) + lo_bf(w.z); a5 += hi_bf(v.z) + hi_bf(w.z);
        a6 += lo_bf(v.w) + lo_bf(w.w); a7 += hi_bf(v.w) + hi_bf(w.w);
    }
    for (; e + 4 <= re; e += 4) {
        int s0 = csr_src[e + q];
        uint4 v = ((const uint4*)(h + (size_t)s0 * 128))[sl];
        a0 += lo_bf(v.x); a1 += hi_bf(v.x); a2 += lo_bf(v.y); a3 += hi_bf(v.y);
        a4 += lo_bf(v.z); a5 += hi_bf(v.z); a6 += lo_bf(v.w); a7 += hi_bf(v.w);
    }
    if (q < re - e) {
        int s0 = csr_src[e + q];
        uint4 v = ((const uint4*)(h + (size_t)s0 * 128))[sl];
        a0 += lo_bf(v.x); a1 += hi_bf(v.x); a2 += lo_bf(v.y); a3 += hi_bf(v.y);
        a4 += lo_bf(v.z); a5 += hi_bf(v.z); a6 += lo_bf(v.w); a7 += hi_bf(v.w);
    }

    a0 += __shfl_xor(a0, 16, 64); a0 += __shfl_xor(a0, 32, 64);
    a1 += __shfl_xor(a1, 16, 64); a1 += __shfl_xor(a1, 32, 64);
    a2 += __shfl_xor(a2, 16, 64); a2 += __shfl_xor(a2, 32, 64);
    a3 += __shfl_xor(a3, 16, 64); a3 += __shfl_xor(a3, 32, 64);
    a4 += __shfl_xor(a4, 16, 64); a4 += __shfl_xor(a4, 32, 64);
    a5 += __shfl_xor(a5, 16, 64); a5 += __shfl_xor(a5, 32, 64);
    a6 += __shfl_xor(a6, 16, 64); a6 += __shfl_xor(a6, 32, 64);
    a7 += __shfl_xor(a7, 16, 64); a7 += __shfl_xor(a7, 32, 64);

    if (q == 0) {
        uint4 o;
        o.x = pack_bf(a0, a1); o.y = pack_bf(a2, a3);
        o.z = pack_bf(a4, a5); o.w = pack_bf(a6, a7);
        ((uint4*)(h2 + (size_t)node * 128))[sl] = o;
    }
}

// ---------------- MFMA GEMM: C = act(A[nrows,K] @ W[K,OUT] * scale + shift) ----------------
// Wt bf16 [OUT][K] PRE-SWIZZLED in global -> linear global_load_lds (width 16) staging;
// ds_read uses XOR swizzle. 4 waves x 2 row-groups = 128 rows/block. (round-17 config)
template <int K, int OUT, bool RELU>
__global__ __launch_bounds__(256) void mfma_gemm_kernel(
    const unsigned short* __restrict__ Ap, const unsigned short* __restrict__ Wt,
    const float* __restrict__ scale, const float* __restrict__ shift,
    unsigned short* __restrict__ Cout, int nrows)
{
    constexpr int NT = OUT / 16;
    constexpr int KS = K / 32;
    constexpr int CH = OUT * K / 8;
    __shared__ unsigned short WtLds[OUT * K];

    const int tid = threadIdx.x;
    const int wv = tid >> 6, lane = tid & 63;
    {
#pragma unroll
        for (int i = 0; i < CH / 256; ++i) {
            unsigned chunk = (unsigned)(i * 256 + wv * 64);
            const char* gsrc = (const char*)Wt + (size_t)(chunk + lane) * 16u;
            char* ldst = (char*)WtLds + (size_t)chunk * 16u;
            __builtin_amdgcn_global_load_lds(
                (const __attribute__((address_space(1))) void*)gsrc,
                (__attribute__((address_space(3))) void*)ldst,
                16, 0, 0);
        }
    }

    const int l15 = lane & 15, lhi = lane >> 4;
    const int rbase = blockIdx.x * 128 + wv * 32;
    const int r0 = rbase + l15;
    const int r1 = rbase + 16 + l15;
    const int rr0 = min(r0, nrows - 1);
    const int rr1 = min(r1, nrows - 1);

    bf16x8 bfrag[2][KS];
    {
        const unsigned short* a0 = Ap + (size_t)rr0 * K + lhi * 8;
        const unsigned short* a1 = Ap + (size_t)rr1 * K + lhi * 8;
#pragma unroll
        for (int ks = 0; ks < KS; ++ks) {
            bfrag[0][ks] = *(const bf16x8*)(a0 + ks * 32);
            bfrag[1][ks] = *(const bf16x8*)(a1 + ks * 32);
        }
    }

    __syncthreads();   // drains vmcnt incl. global_load_lds before ds_read

    f32x4 acc[2][NT];
#pragma unroll
    for (int g = 0; g < 2; ++g)
#pragma unroll
        for (int nt = 0; nt < NT; ++nt) acc[g][nt] = (f32x4){0.f, 0.f, 0.f, 0.f};

#pragma unroll
    for (int ks = 0; ks < KS; ++ks) {
#pragma unroll
        for (int nt = 0; nt < NT; ++nt) {
            int row = nt * 16 + l15;
            unsigned off = ((unsigned)((row * K + ks * 32 + lhi * 8) * 2)) ^ (((unsigned)(l15 & 7u)) << 4);
            bf16x8 wfrag = *(const bf16x8*)((const char*)WtLds + off);
            acc[0][nt] = __builtin_amdgcn_mfma_f32_16x16x32_bf16(wfrag, bfrag[0][ks], acc[0][nt], 0, 0, 0);
            acc[1][nt] = __builtin_amdgcn_mfma_f32_16x16x32_bf16(wfrag, bfrag[1][ks], acc[1][nt], 0, 0, 0);
        }
    }

    const float4* sc4 = (const float4*)scale;
    const float4* sh4 = (const float4*)shift;
#pragma unroll
    for (int g = 0; g < 2; ++g) {
        const int r = (g == 0) ? r0 : r1;
        if (r >= nrows) continue;
#pragma unroll
        for (int nt = 0; nt < NT; ++nt) {
            float4 sc = sc4[nt * 4 + lhi];
            float4 sh = sh4[nt * 4 + lhi];
            float y0 = acc[g][nt][0] * sc.x + sh.x;
            float y1 = acc[g][nt][1] * sc.y + sh.y;
            float y2 = acc[g][nt][2] * sc.z + sh.z;
            float y3 = acc[g][nt][3] * sc.w + sh.w;
            if (RELU) {
                y0 = fmaxf(y0, 0.f); y1 = fmaxf(y1, 0.f);
                y2 = fmaxf(y2, 0.f); y3 = fmaxf(y3, 0.f);
            }
            size_t o = (size_t)r * OUT + nt * 16 + lhi * 4;
            ushort4 p = make_ushort4(f2bf(y0), f2bf(y1), f2bf(y2), f2bf(y3));
            *(ushort4*)(Cout + o) = p;
        }
    }
}

// ---------------- pooling over sorted batch: chunked + boundary atomics ----------------
__global__ __launch_bounds__(128) void pool_kernel(const unsigned short* __restrict__ h,
                                                   const int* __restrict__ batch,
                                                   float* __restrict__ pooled, int N, int chunk) {
    int d = threadIdx.x;
    int start = blockIdx.x * chunk;
    if (start >= N) return;
    int end = min(start + chunk, N);
    float acc = 0.f;
    int g = batch[start];
    for (int r = start; r < end; ++r) {
        int bg = batch[r];
        if (bg != g) {
            atomicAdd(&pooled[g * 128 + d], acc);
            acc = 0.f;
            g = bg;
        }
        acc += bf2f(h[(size_t)r * 128 + d]);
    }
    atomicAdd(&pooled[g * 128 + d], acc);
}

// ---------------- readout MLP ----------------
__global__ __launch_bounds__(128) void readout_kernel(const float* __restrict__ pooled,
                                                      const float* __restrict__ Wr1,
                                                      const float* __restrict__ br1,
                                                      const float* __restrict__ Wr2,
                                                      const float* __restrict__ br2,
                                                      float* __restrict__ out) {
    __shared__ float prow[128];
    __shared__ float t[128];
    int g = blockIdx.x, j = threadIdx.x;
    prow[j] = pooled[g * 128 + j];
    __syncthreads();
    float acc = 0.f;
    for (int k = 0; k < 128; ++k) acc += prow[k] * Wr1[k * 128 + j];
    t[j] = fmaxf(acc + br1[j], 0.f);
    __syncthreads();
    if (j < 10) {
        float a2 = 0.f;
        for (int k = 0; k < 128; ++k) a2 += t[k] * Wr2[k * 10 + j];
        out[g * 10 + j] = a2 + br2[j];
    }
}

extern "C" void kernel_launch(void* const* d_in, const int* in_sizes, int n_in,
                              void* d_out, int out_size, void* d_ws, size_t ws_size,
                              hipStream_t stream) {
    const float* x   = (const float*)d_in[0];
    const int* c2    = (const int*)d_in[1];
    const int* u2    = (const int*)d_in[2];
    const int* batch = (const int*)d_in[3];
    const float* We  = (const float*)d_in[4];
    const float* be  = (const float*)d_in[5];
    const float* W1  = (const float*)d_in[6];
    const float* b1  = (const float*)d_in[7];
    const float* g1  = (const float*)d_in[8];
    const float* bt1 = (const float*)d_in[9];
    const float* m1  = (const float*)d_in[10];
    const float* v1  = (const float*)d_in[11];
    const float* W2  = (const float*)d_in[12];
    const float* b2  = (const float*)d_in[13];
    const float* g2  = (const float*)d_in[14];
    const float* bt2 = (const float*)d_in[15];
    const float* m2  = (const float*)d_in[16];
    const float* v2  = (const float*)d_in[17];
    const float* Wr1 = (const float*)d_in[18];
    const float* br1 = (const float*)d_in[19];
    const float* Wr2 = (const float*)d_in[20];
    const float* br2 = (const float*)d_in[21];

    const int N = in_sizes[3];        // 50000
    const int E = in_sizes[1];        // 800000
    const int L = in_sizes[7] / 256;  // 3
    const int G = out_size / 10;      // 64

    const int NC = (N + 255) / 256;   // 196 coarse buckets (256 nodes each)

    // workspace layout (256B-aligned chunks)
    char* ws = (char*)d_ws;
    size_t off = 0;
    auto alloc = [&](size_t bytes) { char* p = ws + off; off += (bytes + 255) & ~(size_t)255; return p; };
    unsigned short* hb   = (unsigned short*)alloc((size_t)N * 128 * 2);
    unsigned short* h2b  = (unsigned short*)alloc((size_t)N * 128 * 2);
    unsigned short* zb   = (unsigned short*)alloc((size_t)N * 256 * 2);
    unsigned short* Wte  = (unsigned short*)alloc(128 * 128 * 2);
    unsigned short* Wt1  = (unsigned short*)alloc((size_t)L * 256 * 128 * 2);
    unsigned short* Wt2  = (unsigned short*)alloc((size_t)L * 128 * 256 * 2);
    float* sce = (float*)alloc(128 * 4);
    float* she = (float*)alloc(128 * 4);
    float* sc1 = (float*)alloc((size_t)L * 256 * 4);
    float* sh1 = (float*)alloc((size_t)L * 256 * 4);
    float* sc2 = (float*)alloc((size_t)L * 128 * 4);
    float* sh2 = (float*)alloc((size_t)L * 128 * 4);
    float* pooled = (float*)alloc((size_t)G * 128 * 4);
    int* coarse_cnt   = (int*)alloc(512 * 4);       // [0:256) cnt, [256:512) alloc
    int* coarse_alloc = coarse_cnt + 256;
    int* node_start   = (int*)alloc((size_t)(N + 1) * 4);
    int* buck         = (int*)alloc((size_t)E * 4);
    int* csr_src      = (int*)alloc((size_t)E * 4);

    const int ebins = (E + 4095) / 4096;   // 196
    const int gemm_blocks = (N + 127) / 128;   // 391
    const int prep_blocks = 128 * (1 + 2 * L); // 896

    // ---- memsets ----
    hipMemsetAsync(coarse_cnt, 0, 512 * 4, stream);
    hipMemsetAsync(pooled, 0, (size_t)G * 128 * 4, stream);

    // ---- setup A: count_coarse || prep (independent) ----
    setup_a_kernel<<<ebins + prep_blocks, 256, 0, stream>>>(
        u2, coarse_cnt, E, ebins,
        We, W1, W2, Wte, Wt1, Wt2,
        be, b1, g1, bt1, m1, v1, b2, g2, bt2, m2, v2,
        sce, she, sc1, sh1, sc2, sh2, L);

    // ---- setup B: bin_coarse || embed GEMM (deps on A only) ----
    setup_b_kernel<<<ebins + gemm_blocks, 256, 0, stream>>>(
        u2, c2, coarse_cnt, coarse_alloc, buck, E, NC, ebins,
        x, Wte, sce, she, hb, N);

    // ---- CSR finalize ----
    bin_node_kernel<<<NC, 256, 0, stream>>>(coarse_cnt, buck, node_start, csr_src, N, NC);

    // ---- GIN layers ----
    for (int l = 0; l < L; ++l) {
        aggregate_kernel<<<(N + 3) / 4, 256, 0, stream>>>(hb, node_start, csr_src, h2b, N);
        mfma_gemm_kernel<128, 256, true><<<gemm_blocks, 256, 0, stream>>>(
            h2b, Wt1 + (size_t)l * 128 * 256, sc1 + l * 256, sh1 + l * 256, zb, N);
        mfma_gemm_kernel<256, 128, true><<<gemm_blocks, 256, 0, stream>>>(
            zb, Wt2 + (size_t)l * 256 * 128, sc2 + l * 128, sh2 + l * 128, hb, N);
    }

    // ---- pooling + readout ----
    const int pool_blocks = 2048;
    const int chunk = (N + pool_blocks - 1) / pool_blocks;
    pool_kernel<<<pool_blocks, 128, 0, stream>>>(hb, batch, pooled, N, chunk);
    readout_kernel<<<G, 128, 0, stream>>>(pooled, Wr1, br1, Wr2, br2, (float*)d_out);
}